// Round 18
// baseline (594.161 us; speedup 1.0000x reference)
//
#include <hip/hip_runtime.h>

// Qwen3.5 GatedDeltaNet fwd on gfx950 — chunked delta-rule + 8-phase 256^2 GEMM.
// B=2 T=2048 HID=2048 HK=16 HV=32 DK=DV=128 KW=4, chunk C=64 (32 chunks).
// R18: gemm8p sync-before-MFMA reorder (m201 pattern) — each vmcnt+barrier moved
// ahead of its MFMA cluster; waves free-run from MFMA into next phase's reads.

#define T_LEN 2048
#define MROWS 4096

typedef __bf16 bf16x8 __attribute__((ext_vector_type(8)));
typedef float f32x4 __attribute__((ext_vector_type(4)));

#define MFMA(a, b, c) __builtin_amdgcn_mfma_f32_16x16x32_bf16((a), (b), (c), 0, 0, 0)

__device__ __forceinline__ unsigned short f2bf(float f) {
  unsigned int u = __float_as_uint(f);
  unsigned int r = (u + 0x7fffu + ((u >> 16) & 1u)) >> 16;
  return (unsigned short)r;
}
__device__ __forceinline__ float bf2f(unsigned short u) {
  return __uint_as_float(((unsigned int)u) << 16);
}
__device__ __forceinline__ void gload_lds16(const void* g, void* l) {
  __builtin_amdgcn_global_load_lds(
      (const __attribute__((address_space(1))) unsigned int*)g,
      (__attribute__((address_space(3))) unsigned int*)l, 16, 0, 0);
}

// ---------------- transpose f32 [R,C] -> bf16 [C,R] (W_out) ----------------
__global__ __launch_bounds__(256) void transpose_f2b(const float* __restrict__ src,
                                                     unsigned short* __restrict__ dst,
                                                     int R, int C) {
  __shared__ float tile[32][33];
  int tx = threadIdx.x & 31, ty = threadIdx.x >> 5;
  int c0 = blockIdx.x * 32, r0 = blockIdx.y * 32;
  #pragma unroll
  for (int i = ty; i < 32; i += 8)
    tile[i][tx] = src[(size_t)(r0 + i) * C + c0 + tx];
  __syncthreads();
  #pragma unroll
  for (int i = ty; i < 32; i += 8)
    dst[(size_t)(c0 + i) * R + r0 + tx] = f2bf(tile[tx][i]);
}

// ------- merged: W_qkv/W_z/W_b/W_a transposes + x f32->bf16 convert -------
__global__ __launch_bounds__(256) void transpose_multi(const float* __restrict__ Wqkv,
                                                       const float* __restrict__ Wz,
                                                       const float* __restrict__ Wb,
                                                       const float* __restrict__ Wa,
                                                       const float* __restrict__ x,
                                                       unsigned short* __restrict__ WallT,
                                                       unsigned short* __restrict__ WbaT,
                                                       unsigned short* __restrict__ x_bf) {
  int bid = blockIdx.x;
  if (bid >= 24704) {   // x convert: 8192 blocks over 2,097,152 float4
    int i = (bid - 24704) * 256 + threadIdx.x;
    float4 v = ((const float4*)x)[i];
    ushort4 o;
    o.x = f2bf(v.x); o.y = f2bf(v.y); o.z = f2bf(v.z); o.w = f2bf(v.w);
    ((ushort4*)x_bf)[i] = o;
    return;
  }
  const float* src; unsigned short* dst; int C, cx, ry;
  if (bid < 16384)                 { src = Wqkv; dst = WallT; C = 8192; cx = bid & 255; ry = bid >> 8; }
  else if ((bid -= 16384) < 8192)  { src = Wz; dst = WallT + (size_t)8192 * 2048; C = 4096; cx = bid & 127; ry = bid >> 7; }
  else if ((bid -= 8192) < 64)     { src = Wb; dst = WbaT; C = 32; cx = 0; ry = bid; }
  else { bid -= 64;                  src = Wa; dst = WbaT + (size_t)32 * 2048; C = 32; cx = 0; ry = bid; }
  const int R = 2048;
  __shared__ float tile[32][33];
  int tx = threadIdx.x & 31, ty = threadIdx.x >> 5;
  int c0 = cx * 32, r0 = ry * 32;
  #pragma unroll
  for (int i = ty; i < 32; i += 8)
    if (c0 + tx < C) tile[i][tx] = src[(size_t)(r0 + i) * C + c0 + tx];
  __syncthreads();
  #pragma unroll
  for (int i = ty; i < 32; i += 8)
    if (c0 + i < C) dst[(size_t)(c0 + i) * R + r0 + tx] = f2bf(tile[tx][i]);
}

// ============ 8-phase 256^2 GEMM with split output (cols<Nsplit -> Cv, else Cv2) ============
template <int OUTBF>
__global__ __launch_bounds__(512, 2) void gemm8p(const unsigned short* __restrict__ A, int lda,
                                                 const unsigned short* __restrict__ Bt, int ldb,
                                                 void* __restrict__ Cv, int ldc,
                                                 int Nsplit, void* __restrict__ Cv2, int ldc2,
                                                 int M, int N, int K) {
  __shared__ unsigned short lds[65536];   // 128 KB

  const int mtiles = M >> 8;
  const int nwg = gridDim.x, orig = blockIdx.x;
  const int q = nwg >> 3, r = nwg & 7;
  const int xcd = orig & 7, idx = orig >> 3;
  const int swz = (xcd < r ? xcd * (q + 1) : r * (q + 1) + (xcd - r) * q) + idx;
  const int m0 = (swz % mtiles) * 256;
  const int n0 = (swz / mtiles) * 256;

  const int tid = threadIdx.x, lane = tid & 63, wv = tid >> 6;
  const int wm = wv >> 2, wn = wv & 3;
  const int l15 = lane & 15, l4 = lane >> 4;

  f32x4 acc[8][4];
  #pragma unroll
  for (int i = 0; i < 8; i++)
    #pragma unroll
    for (int j = 0; j < 4; j++) acc[i][j] = f32x4{0.f, 0.f, 0.f, 0.f};

  const int NT = K >> 6;

  auto SHALF = [&](int t, int op, int h) {
    unsigned short* base = lds + (t & 1) * 32768 + op * 16384 + h * 8192;
    const unsigned short* G = op ? Bt : A;
    const int ld = op ? ldb : lda;
    const int r0g = (op ? n0 : m0) + h * 128;
    const int k0 = t << 6;
    #pragma unroll
    for (int is = 0; is < 2; is++) {
      int ow = is * 8192 + wv * 1024;
      int o = ow + lane * 16;
      int row = o >> 7, colB = o & 127;
      int scol = colB ^ ((row & 7) << 4);
      gload_lds16(G + (size_t)(r0g + row) * ld + k0 + (scol >> 1), base + (ow >> 1));
    }
  };

  bf16x8 aF[4][2], bF[2][2], bF0[2][2];
  auto RD_A = [&](int t, int qm) {
    const unsigned short* base = lds + (t & 1) * 32768 + qm * 8192;
    #pragma unroll
    for (int mi = 0; mi < 4; mi++) {
      int ra = wm * 64 + mi * 16 + l15;
      int sw = (ra & 7) << 4;
      #pragma unroll
      for (int kh = 0; kh < 2; kh++) {
        int colB = kh * 64 + l4 * 16;
        aF[mi][kh] = *(const bf16x8*)(base + ra * 64 + ((colB ^ sw) >> 1));
      }
    }
  };
  auto RD_B = [&](int t, int qn, bf16x8 (&bdst)[2][2]) {
    const unsigned short* base = lds + (t & 1) * 32768 + 16384 + qn * 8192;
    #pragma unroll
    for (int ni = 0; ni < 2; ni++) {
      int rb = wn * 32 + ni * 16 + l15;
      int sw = (rb & 7) << 4;
      #pragma unroll
      for (int kh = 0; kh < 2; kh++) {
        int colB = kh * 64 + l4 * 16;
        bdst[ni][kh] = *(const bf16x8*)(base + rb * 64 + ((colB ^ sw) >> 1));
      }
    }
  };
  auto COMPUTE = [&](int qm, int qn, const bf16x8 (&bsrc)[2][2]) {
    __builtin_amdgcn_s_setprio(1);
    #pragma unroll
    for (int mi = 0; mi < 4; mi++)
      #pragma unroll
      for (int ni = 0; ni < 2; ni++)
        #pragma unroll
        for (int kh = 0; kh < 2; kh++)
          acc[qm * 4 + mi][qn * 2 + ni] =
              MFMA(aF[mi][kh], bsrc[ni][kh], acc[qm * 4 + mi][qn * 2 + ni]);
    __builtin_amdgcn_s_setprio(0);
  };
  auto SBAR = [&]() {
    __builtin_amdgcn_sched_barrier(0);
    __builtin_amdgcn_s_barrier();
    __builtin_amdgcn_sched_barrier(0);
  };

  // prologue: stage tile0 fully, publish
  SHALF(0, 0, 0); SHALF(0, 1, 0); SHALF(0, 1, 1); SHALF(0, 0, 1);
  asm volatile("s_waitcnt vmcnt(0)" ::: "memory");
  SBAR();

  for (int t = 0; t < NT; t++) {
    const bool lastT = (t + 1 >= NT);
    // ph0: reads + staging first, sync (completes B1[t]), then MFMA
    RD_A(t, 0); RD_B(t, 0, bF0);
    if (!lastT) {
      SHALF(t + 1, 0, 0);
      asm volatile("s_waitcnt vmcnt(4)" ::: "memory");
    } else {
      asm volatile("s_waitcnt vmcnt(2)" ::: "memory");
    }
    SBAR();
    COMPUTE(0, 0, bF0);
    // ph1: sync completes A1[t]
    RD_B(t, 1, bF);
    if (!lastT) {
      SHALF(t + 1, 1, 0);
      asm volatile("s_waitcnt vmcnt(4)" ::: "memory");
    } else {
      asm volatile("s_waitcnt vmcnt(0)" ::: "memory");
    }
    SBAR();
    COMPUTE(0, 1, bF);
    // ph2: no sync needed (A1[t] published at ph1 sync)
    RD_A(t, 1);
    if (!lastT) SHALF(t + 1, 1, 1);
    COMPUTE(1, 1, bF);
    // ph3: boundary sync BEFORE the reg-only MFMA cluster (completes A0,B0[t+1])
    if (!lastT) {
      SHALF(t + 1, 0, 1);
      asm volatile("s_waitcnt vmcnt(4)" ::: "memory");
      SBAR();
    }
    COMPUTE(1, 0, bF0);
  }

  #pragma unroll
  for (int i = 0; i < 8; i++) {
    int grow = m0 + (i >> 2) * 128 + wm * 64 + (i & 3) * 16 + l4 * 4;
    #pragma unroll
    for (int j = 0; j < 4; j++) {
      int gcol = n0 + (j >> 1) * 128 + wn * 32 + (j & 1) * 16 + l15;
      if (OUTBF) {
        if (gcol < Nsplit) {
          unsigned short* cp = (unsigned short*)Cv + (size_t)grow * ldc + gcol;
          #pragma unroll
          for (int rr = 0; rr < 4; rr++) cp[(size_t)rr * ldc] = f2bf(acc[i][j][rr]);
        } else {
          unsigned short* cp = (unsigned short*)Cv2 + (size_t)grow * ldc2 + (gcol - Nsplit);
          #pragma unroll
          for (int rr = 0; rr < 4; rr++) cp[(size_t)rr * ldc2] = f2bf(acc[i][j][rr]);
        }
      } else {
        float* cp = (float*)Cv + (size_t)grow * ldc + gcol;
        #pragma unroll
        for (int rr = 0; rr < 4; rr++) cp[(size_t)rr * ldc] = acc[i][j][rr];
      }
    }
  }
}

// ===================== 256-wide-tile GEMM (classic, GEMM3) =====================
template <int OUTBF, int BN>
__global__ __launch_bounds__(512, 2) void gemm256(const unsigned short* __restrict__ A, int lda,
                                                  const unsigned short* __restrict__ Bt, int ldb,
                                                  void* __restrict__ Cv, int ldc,
                                                  int M, int N, int K) {
  constexpr int BUFSZ = 16384 + BN * 64;
  constexpr int BISS = BN / 64;
  constexpr int IS = 4 + BISS;
  constexpr int WMv = (BN == 256) ? 2 : 4;
  constexpr int MSUB = 256 / (WMv * 16);
  constexpr int MSPAN = 256 / WMv;

  __shared__ unsigned short lds[2 * BUFSZ];

  const int mtiles = M >> 8;
  const int nwg = gridDim.x;
  const int orig = blockIdx.x;
  const int q = nwg >> 3, r = nwg & 7;
  const int xcd = orig & 7, idx = orig >> 3;
  const int swz = (xcd < r ? xcd * (q + 1) : r * (q + 1) + (xcd - r) * q) + idx;
  const int m0 = (swz % mtiles) * 256;
  const int n0 = (swz / mtiles) * BN;

  const int tid = threadIdx.x, lane = tid & 63, wv = tid >> 6;
  const int wm = (BN == 256) ? (wv >> 2) : (wv >> 1);
  const int wn = (BN == 256) ? (wv & 3) : (wv & 1);
  const int l15 = lane & 15, l4 = lane >> 4;

  f32x4 acc[MSUB][4];
  #pragma unroll
  for (int i = 0; i < MSUB; i++)
    #pragma unroll
    for (int j = 0; j < 4; j++) acc[i][j] = f32x4{0.f, 0.f, 0.f, 0.f};

  const int NT = K >> 6;

  auto STAGE = [&](int kt) {
    unsigned short* base = lds + (kt & 1) * BUFSZ;
    const int k0 = kt << 6;
    #pragma unroll
    for (int is = 0; is < 4; is++) {
      int ow = is * 8192 + wv * 1024;
      int o = ow + lane * 16;
      int row = o >> 7, colB = o & 127;
      int scol = colB ^ ((row & 7) << 4);
      gload_lds16(A + (size_t)(m0 + row) * lda + k0 + (scol >> 1), base + (ow >> 1));
    }
    #pragma unroll
    for (int is = 0; is < BISS; is++) {
      int ow = is * 8192 + wv * 1024;
      int o = ow + lane * 16;
      int row = o >> 7, colB = o & 127;
      int scol = colB ^ ((row & 7) << 4);
      gload_lds16(Bt + (size_t)(n0 + row) * ldb + k0 + (scol >> 1), base + 16384 + (ow >> 1));
    }
  };

  STAGE(0);
  if (NT > 1) STAGE(1);
  if constexpr (IS == 8) asm volatile("s_waitcnt vmcnt(8)" ::: "memory");
  else                   asm volatile("s_waitcnt vmcnt(6)" ::: "memory");
  __builtin_amdgcn_sched_barrier(0);
  __builtin_amdgcn_s_barrier();
  __builtin_amdgcn_sched_barrier(0);

  for (int t = 0; t < NT; t++) {
    const unsigned short* Abuf = lds + (t & 1) * BUFSZ;
    const unsigned short* Bbuf = Abuf + 16384;
    bf16x8 bF[4][2];
    #pragma unroll
    for (int n = 0; n < 4; n++) {
      int rb = wn * 64 + n * 16 + l15;
      int sw = (rb & 7) << 4;
      #pragma unroll
      for (int ks = 0; ks < 2; ks++) {
        int colB = (ks * 32 + l4 * 8) * 2;
        bF[n][ks] = *(const bf16x8*)(Bbuf + rb * 64 + ((colB ^ sw) >> 1));
      }
    }
    __builtin_amdgcn_s_setprio(1);
    #pragma unroll
    for (int m = 0; m < MSUB; m++) {
      int ra = wm * MSPAN + m * 16 + l15;
      int sw = (ra & 7) << 4;
      int c0b = l4 * 16;
      bf16x8 a0 = *(const bf16x8*)(Abuf + ra * 64 + ((c0b ^ sw) >> 1));
      bf16x8 a1 = *(const bf16x8*)(Abuf + ra * 64 + (((64 + c0b) ^ sw) >> 1));
      #pragma unroll
      for (int n = 0; n < 4; n++) {
        acc[m][n] = MFMA(a0, bF[n][0], acc[m][n]);
        acc[m][n] = MFMA(a1, bF[n][1], acc[m][n]);
      }
    }
    __builtin_amdgcn_s_setprio(0);
    __builtin_amdgcn_sched_barrier(0);
    __builtin_amdgcn_s_barrier();
    __builtin_amdgcn_sched_barrier(0);
    if (t + 2 < NT) STAGE(t + 2);
    if (t + 1 < NT) {
      if (t + 2 < NT) {
        if constexpr (IS == 8) asm volatile("s_waitcnt vmcnt(8)" ::: "memory");
        else                   asm volatile("s_waitcnt vmcnt(6)" ::: "memory");
      } else {
        asm volatile("s_waitcnt vmcnt(0)" ::: "memory");
      }
      __builtin_amdgcn_sched_barrier(0);
      __builtin_amdgcn_s_barrier();
      __builtin_amdgcn_sched_barrier(0);
    }
  }

  #pragma unroll
  for (int m = 0; m < MSUB; m++) {
    int grow = m0 + wm * MSPAN + m * 16 + l4 * 4;
    #pragma unroll
    for (int n = 0; n < 4; n++) {
      int gcol = n0 + wn * 64 + n * 16 + l15;
      if (OUTBF) {
        unsigned short* cp = (unsigned short*)Cv + (size_t)grow * ldc + gcol;
        #pragma unroll
        for (int rr = 0; rr < 4; rr++) cp[(size_t)rr * ldc] = f2bf(acc[m][n][rr]);
      } else {
        float* cp = (float*)Cv + (size_t)grow * ldc + gcol;
        #pragma unroll
        for (int rr = 0; rr < 4; rr++) cp[(size_t)rr * ldc] = acc[m][n][rr];
      }
    }
  }
}

// ------- ba-GEMM (128^2) with fused beta/g epilogue -------
__global__ __launch_bounds__(256) void gemm_ba(const unsigned short* __restrict__ A, int lda,
                                               const unsigned short* __restrict__ Bt, int ldb,
                                               const float* __restrict__ A_log,
                                               const float* __restrict__ dt_bias,
                                               unsigned short* __restrict__ betab,
                                               float* __restrict__ g,
                                               int M, int K) {
  __shared__ unsigned short As[128 * 64];
  __shared__ unsigned short Bs[128 * 64];
  const int tid = threadIdx.x, lane = tid & 63, wv = tid >> 6;
  const int wr = wv >> 1, wc = wv & 1;
  const int m0 = blockIdx.y * 128;
  const int lrow8 = lane >> 3;
  const int lk8 = (lane & 7) * 8;

  f32x4 acc[4][4];
  #pragma unroll
  for (int i = 0; i < 4; i++)
    #pragma unroll
    for (int j = 0; j < 4; j++) acc[i][j] = f32x4{0.f, 0.f, 0.f, 0.f};

  for (int k0 = 0; k0 < K; k0 += 64) {
    #pragma unroll
    for (int j = 0; j < 4; ++j) {
      int chunk = j * 4 + wv;
      int r = chunk * 8 + lrow8;
      gload_lds16(A + (size_t)(m0 + r) * lda + k0 + lk8, (void*)(As + chunk * 512));
      gload_lds16(Bt + (size_t)r * ldb + k0 + lk8, (void*)(Bs + chunk * 512));
    }
    __syncthreads();
    #pragma unroll
    for (int half = 0; half < 2; ++half) {
      int ko = half * 32 + (lane >> 4) * 8;
      bf16x8 af[4], bfr[4];
      #pragma unroll
      for (int i = 0; i < 4; i++) {
        int ra = wr * 64 + i * 16 + (lane & 15);
        af[i] = *(const bf16x8*)(As + ra * 64 + ko);
        int rb = wc * 64 + i * 16 + (lane & 15);
        bfr[i] = *(const bf16x8*)(Bs + rb * 64 + ko);
      }
      #pragma unroll
      for (int i = 0; i < 4; i++)
        #pragma unroll
        for (int j = 0; j < 4; j++)
          acc[i][j] = MFMA(af[i], bfr[j], acc[i][j]);
    }
    __syncthreads();
  }
  int cr4 = (lane >> 4) * 4;
  int cc = lane & 15;
  #pragma unroll
  for (int i = 0; i < 4; i++) {
    int row = m0 + wr * 64 + i * 16 + cr4;
    #pragma unroll
    for (int j = 0; j < 4; j++) {
      int col = wc * 64 + j * 16 + cc;
      if (col < 64) {
        #pragma unroll
        for (int r = 0; r < 4; r++) {
          int erow = row + r;
          float a = acc[i][j][r];
          if (col < 32) {
            betab[(size_t)erow * 32 + col] = f2bf(1.f / (1.f + expf(-a)));
          } else {
            int hvv = col - 32;
            float xg = a + dt_bias[hvv];
            float sp = (xg > 20.f) ? xg : log1pf(expf(xg));
            g[(size_t)erow * 32 + hvv] = -expf(A_log[hvv]) * sp;
          }
        }
      }
    }
  }
}

// ------- conv4 + SiLU + q/k l2norm -------
__global__ __launch_bounds__(256) void conv_kernel(const unsigned short* __restrict__ qkv,
                                                   const float* __restrict__ conv_w,
                                                   unsigned short* __restrict__ out) {
  const int seg = blockIdx.x, tt = blockIdx.y, b = blockIdx.z;
  const int tid = threadIdx.x;
  const int c0 = seg * 128;
  const bool isq = seg < 16;
  int scb;
  if (isq) scb = seg * 512;
  else if (seg < 32) scb = (seg - 16) * 512 + 128;
  else scb = ((seg - 32) >> 1) * 512 + 256 + ((seg - 32) & 1) * 128;

  __shared__ unsigned short raw[35][136];
  __shared__ float cw[4][132];

  for (int i = tid; i < 512; i += 256) {
    int cl = i >> 2, tap = i & 3;
    cw[tap][cl] = conv_w[(size_t)(c0 + cl) * 4 + tap];
  }
  const int t0 = tt * 32;
  for (int i = tid; i < 560; i += 256) {
    int row = i >> 4, col = (i & 15) * 8;
    int gt = t0 - 3 + row;
    uint4 v = make_uint4(0u, 0u, 0u, 0u);
    if (gt >= 0) v = *(const uint4*)(qkv + (size_t)(b * T_LEN + gt) * 8192 + scb + col);
    *(uint4*)(&raw[row][col]) = v;
  }
  __syncthreads();
  const int s = tid >> 3, dg = tid & 7;
  union RawU { uint4 v[2]; unsigned short h[16]; };
  RawU u[4];
  #pragma unroll
  for (int i = 0; i < 4; i++) {
    const uint4* p = (const uint4*)&raw[s + i][dg * 16];
    u[i].v[0] = p[0]; u[i].v[1] = p[1];
  }
  float vals[16]; float ss = 0.f;
  #pragma unroll
  for (int j = 0; j < 16; j++) {
    float a = 0.f;
    #pragma unroll
    for (int i = 0; i < 4; i++) a = fmaf(cw[i][dg * 16 + j], bf2f(u[i].h[j]), a);
    a = a / (1.f + expf(-a));
    vals[j] = a; ss += a * a;
  }
  if (seg < 32) {
    ss += __shfl_xor(ss, 1); ss += __shfl_xor(ss, 2); ss += __shfl_xor(ss, 4);
    float sc = rsqrtf(ss + 1e-6f);
    if (isq) sc *= 0.08838834764831845f;
    #pragma unroll
    for (int j = 0; j < 16; j++) vals[j] *= sc;
  }
  union { uint4 v[2]; unsigned short h[16]; } ov;
  #pragma unroll
  for (int j = 0; j < 16; j++) ov.h[j] = f2bf(vals[j]);
  unsigned short* op = out + (size_t)(b * T_LEN + t0 + s) * 8192 + c0 + dg * 16;
  *(uint4*)(op) = ov.v[0];
  *(uint4*)(op + 8) = ov.v[1];
}

// ---------------- prep: per chunk-head precompute M1, M2, vecs ----------------
__global__ __launch_bounds__(256) void prep_kernel(const unsigned short* __restrict__ conv,
                                                   const float* __restrict__ g,
                                                   const unsigned short* __restrict__ betab,
                                                   unsigned short* __restrict__ M1g,
                                                   unsigned short* __restrict__ M2g,
                                                   unsigned char* __restrict__ vecs) {
  const int c = blockIdx.x, bh = blockIdx.y;
  const int b = bh >> 5, hv = bh & 31, hk = hv >> 1;
  const int bhc = bh * 32 + c;
  const int tid = threadIdx.x, lane = tid & 63, wv = tid >> 6;
  const int r0 = b * T_LEN + c * 64;
  const int l15 = lane & 15, l4 = lane >> 4;

  __shared__ unsigned short Kb[128 * 72];
  __shared__ unsigned short QbX[64 * 136];
  __shared__ unsigned short Lbf[64 * 72];
  __shared__ unsigned short Pb[64 * 72];
  __shared__ unsigned short WT[3 * 16 * 40];
  __shared__ float Gs[64], SCs[64], BLs[64];

  unsigned short* Qb = QbX;
  unsigned short* XTb = QbX;
  unsigned short* Xdrow = QbX + 4608;

  if (wv == 0) {
    float gt = g[(size_t)(r0 + lane) * 32 + hv];
    #pragma unroll
    for (int d = 1; d < 64; d <<= 1) {
      float o = __shfl_up(gt, (unsigned)d, 64);
      if (lane >= d) gt += o;
    }
    float GC = __shfl(gt, 63, 64);
    float lam = expf(gt);
    float beta = bf2f(betab[(size_t)(r0 + lane) * 32 + hv]);
    Gs[lane] = gt;
    SCs[lane] = expf(GC - gt);
    BLs[lane] = beta;
    unsigned short* vb16 = (unsigned short*)(vecs + (size_t)bhc * 272);
    vb16[lane] = f2bf(beta * lam);
    vb16[64 + lane] = f2bf(lam);
    if (lane == 0) *(float*)(vecs + (size_t)bhc * 272 + 256) = expf(GC);
  }
  const unsigned short* Kg = conv + (size_t)r0 * 8192 + 2048 + hk * 128;
  const unsigned short* Qg = conv + (size_t)r0 * 8192 + hk * 128;
  for (int u = tid; u < 1024; u += 256) {
    int row = u >> 4, col = (u & 15) * 8;
    *(uint4*)(&Kb[row * 136 + col]) = *(const uint4*)(Kg + (size_t)row * 8192 + col);
    *(uint4*)(&Qb[row * 136 + col]) = *(const uint4*)(Qg + (size_t)row * 8192 + col);
  }
  __syncthreads();

  {
    f32x4 akk[4], aqk[4];
    #pragma unroll
    for (int st = 0; st < 4; st++) { akk[st] = f32x4{0,0,0,0}; aqk[st] = f32x4{0,0,0,0}; }
    int trow = wv * 16 + l15;
    int klo = l4 * 8;
    #pragma unroll
    for (int ks = 0; ks < 4; ks++) {
      int ko = ks * 32 + klo;
      bf16x8 ak = *(const bf16x8*)(&Kb[trow * 136 + ko]);
      bf16x8 aq = *(const bf16x8*)(&Qb[trow * 136 + ko]);
      #pragma unroll
      for (int st = 0; st < 4; st++) {
        bf16x8 bk = *(const bf16x8*)(&Kb[(st * 16 + l15) * 136 + ko]);
        akk[st] = MFMA(ak, bk, akk[st]);
        aqk[st] = MFMA(aq, bk, aqk[st]);
      }
    }
    int orow = wv * 16 + l4 * 4;
    int oc = l15;
    #pragma unroll
    for (int st = 0; st < 4; st++)
      #pragma unroll
      for (int r = 0; r < 4; r++) {
        int t = orow + r, ssv = st * 16 + oc;
        float e = expf(fminf(Gs[t] - Gs[ssv], 0.f));
        Lbf[t * 72 + ssv] = f2bf((ssv < t) ? BLs[t] * e * akk[st][r] : 0.f);
        Pb[t * 72 + ssv] = f2bf((ssv <= t) ? e * aqk[st][r] : 0.f);
      }
  }
  __syncthreads();

  unsigned short ktv[32];
  {
    int dk = tid >> 1, tb = (tid & 1) * 32;
    #pragma unroll
    for (int i = 0; i < 32; i++)
      ktv[i] = f2bf(bf2f(Kb[(tb + i) * 136 + dk]) * SCs[tb + i]);
    for (int u = tid; u < 896; u += 256) {
      *(uint4*)(&QbX[u * 8]) = make_uint4(0u, 0u, 0u, 0u);
    }
    for (int u = tid; u < 240; u += 256) {
      *(uint4*)(&WT[u * 8]) = make_uint4(0u, 0u, 0u, 0u);
    }
  }
  __syncthreads();

  {
    int dk = tid >> 1, tb = (tid & 1) * 32;
    #pragma unroll
    for (int i = 0; i < 32; i++) Kb[dk * 72 + tb + i] = ktv[i];
  }
  {
    const int w16 = wv * 16;
    const int cc = l15;
    float xr[16];
    #pragma unroll
    for (int t = 0; t < 16; t++) {
      float acc = (cc == t) ? 1.f : 0.f;
      union { uint4 v[2]; unsigned short h[16]; } rw;
      const uint4* p = (const uint4*)(&Lbf[(w16 + t) * 72 + w16]);
      rw.v[0] = p[0]; rw.v[1] = p[1];
      #pragma unroll
      for (int s = 0; s < 16; s++) {
        if (s < t) acc = fmaf(-bf2f(rw.h[s]), xr[s], acc);
      }
      xr[t] = acc;
    }
    if (lane < 16) {
      #pragma unroll
      for (int t = 0; t < 16; t++) {
        unsigned short v = f2bf(xr[t]);
        XTb[(w16 + cc) * 72 + w16 + t] = v;
        Xdrow[wv * 640 + t * 40 + cc] = v;
      }
    }
  }
  __syncthreads();

  if (wv < 3) {
    const int j = wv;
    for (int i = j + 1; i < 4; i++) {
      f32x4 w_ = f32x4{0.f, 0.f, 0.f, 0.f};
      #pragma unroll
      for (int ks = 0; ks < 2; ks++) {
        int so = ks * 32 + l4 * 8;
        bf16x8 af = *(const bf16x8*)(&Lbf[(i * 16 + l15) * 72 + so]);
        bf16x8 bfv = *(const bf16x8*)(&XTb[(j * 16 + l15) * 72 + so]);
        w_ = MFMA(af, bfv, w_);
      }
      #pragma unroll
      for (int r = 0; r < 4; r++)
        WT[j * 640 + l15 * 40 + l4 * 4 + r] = f2bf(-w_[r]);
      f32x4 xij = f32x4{0.f, 0.f, 0.f, 0.f};
      {
        bf16x8 af = *(const bf16x8*)(&Xdrow[i * 640 + l15 * 40 + l4 * 8]);
        bf16x8 bfv = *(const bf16x8*)(&WT[j * 640 + l15 * 40 + l4 * 8]);
        xij = MFMA(af, bfv, xij);
      }
      #pragma unroll
      for (int r = 0; r < 4; r++)
        XTb[(j * 16 + l15) * 72 + i * 16 + l4 * 4 + r] = f2bf(xij[r]);
    }
  }
  __syncthreads();

  for (int tt = wv * 12; tt < wv * 12 + 12; tt++) {
    f32x4 acc = f32x4{0, 0, 0, 0};
    const unsigned short* Abase;
    int mrow, jc;
    if (tt < 16) { mrow = (tt >> 2) * 16; jc = (tt & 3) * 16; Abase = Pb + mrow * 72; }
    else { int i2 = tt - 16; mrow = (i2 >> 2) * 16; jc = (i2 & 3) * 16; Abase = Kb + mrow * 72; }
    #pragma unroll
    for (int ks = 0; ks < 2; ks++) {
      int so = ks * 32 + l4 * 8;
      bf16x8 af = *(const bf16x8*)(Abase + l15 * 72 + so);
      bf16x8 bfv = *(const bf16x8*)(&XTb[(jc + l15) * 72 + so]);
      acc = MFMA(af, bfv, acc);
    }
    int ro = mrow + l4 * 4, co = jc + l15;
    if (tt < 16) {
      #pragma unroll
      for (int r = 0; r < 4; r++)
        M1g[(size_t)bhc * 4096 + (ro + r) * 64 + co] = f2bf(acc[r]);
    } else {
      #pragma unroll
      for (int r = 0; r < 4; r++)
        M2g[(size_t)bhc * 8192 + (ro + r) * 64 + co] = f2bf(acc[r]);
    }
  }
}

// ---------------- sequential chunk recurrence ----------------
// grid (2 dv-halves, 64 bh); block 512 (8 waves). S-state in registers.
__global__ __launch_bounds__(512) void seq_kernel(unsigned short* __restrict__ conv,
                                                  const unsigned short* __restrict__ M1g,
                                                  const unsigned short* __restrict__ M2g,
                                                  const unsigned char* __restrict__ vecs,
                                                  const unsigned short* __restrict__ betab) {
  const int dvh = blockIdx.x * 64;
  const int bh = blockIdx.y;
  const int b = bh >> 5, hv = bh & 31, hk = hv >> 1;
  const int tid = threadIdx.x, lane = tid & 63, wv = tid >> 6;
  const int l15 = lane & 15, l4 = lane >> 4;

  __shared__ unsigned short Kb[64 * 136], Qb[64 * 136];
  __shared__ unsigned short Vb[64 * 72];
  __shared__ unsigned short S0T[64 * 136];
  __shared__ unsigned short rhsT[64 * 72];
  __shared__ unsigned short bts[64];

  f32x4 S[4];
  #pragma unroll
  for (int i = 0; i < 4; i++) S[i] = f32x4{0.f, 0.f, 0.f, 0.f};

  for (int i = tid; i < 1088; i += 512) *(uint4*)(&S0T[i * 8]) = make_uint4(0u, 0u, 0u, 0u);
  __syncthreads();

  const int trt = (wv >> 1) * 16;
  const int dsb = (wv & 1) * 32;
  const int dkb = wv * 16;

  for (int c = 0; c < 32; c++) {
    const int r0 = b * T_LEN + c * 64;
    const int bhc = bh * 32 + c;
    const unsigned char* vb = vecs + (size_t)bhc * 272;
    const unsigned short* vb16 = (const unsigned short*)vb;
    #pragma unroll
    for (int j = 0; j < 2; j++) {
      int u = j * 512 + tid;
      int row = u >> 4, col = (u & 15) * 8;
      uint4 kv = *(const uint4*)(conv + (size_t)(r0 + row) * 8192 + 2048 + hk * 128 + col);
      uint4 qv = *(const uint4*)(conv + (size_t)(r0 + row) * 8192 + hk * 128 + col);
      *(uint4*)(&Kb[row * 136 + col]) = kv;
      float lam = bf2f(vb16[64 + row]);
      union { uint4 u4; unsigned short h[8]; } qq; qq.u4 = qv;
      #pragma unroll
      for (int e = 0; e < 8; e++) qq.h[e] = f2bf(bf2f(qq.h[e]) * lam);
      *(uint4*)(&Qb[row * 136 + col]) = qq.u4;
    }
    {
      int row = tid >> 3, col = (tid & 7) * 8;
      *(uint4*)(&Vb[row * 72 + col]) =
          *(const uint4*)(conv + (size_t)(r0 + row) * 8192 + 4096 + hv * 128 + dvh + col);
      if (tid < 64) bts[tid] = betab[(size_t)(r0 + tid) * 32 + hv];
    }
    __syncthreads();   // B0
    #pragma unroll
    for (int dt = 0; dt < 2; dt++) {
      int dv0 = dsb + dt * 16;
      f32x4 acc = f32x4{0, 0, 0, 0};
      #pragma unroll
      for (int ks = 0; ks < 4; ks++) {
        int ko = ks * 32 + l4 * 8;
        bf16x8 af = *(const bf16x8*)(&Kb[(trt + l15) * 136 + ko]);
        bf16x8 bfv = *(const bf16x8*)(&S0T[(dv0 + l15) * 136 + ko]);
        acc = MFMA(af, bfv, acc);
      }
      #pragma unroll
      for (int r = 0; r < 4; r++) {
        int tl = trt + l4 * 4 + r;
        float beta = bf2f(bts[tl]);
        float bl = bf2f(vb16[tl]);
        float vv = bf2f(Vb[tl * 72 + dv0 + l15]);
        rhsT[(dv0 + l15) * 72 + tl] = f2bf(beta * vv - bl * acc[r]);
      }
    }
    __syncthreads();   // B1
    {
      const unsigned short* m1b = M1g + (size_t)bhc * 4096;
      #pragma unroll
      for (int dt = 0; dt < 2; dt++) {
        int dv0 = dsb + dt * 16;
        f32x4 acc = f32x4{0, 0, 0, 0};
        #pragma unroll
        for (int ks = 0; ks < 2; ks++) {
          int so = ks * 32 + l4 * 8;
          union { uint4 u4; bf16x8 h; } af;
          af.u4 = *(const uint4*)(m1b + (trt + l15) * 64 + so);
          bf16x8 bfv = *(const bf16x8*)(&rhsT[(dv0 + l15) * 72 + so]);
          acc = MFMA(af.h, bfv, acc);
        }
        #pragma unroll
        for (int ks = 0; ks < 4; ks++) {
          int ko = ks * 32 + l4 * 8;
          bf16x8 af = *(const bf16x8*)(&Qb[(trt + l15) * 136 + ko]);
          bf16x8 bfv = *(const bf16x8*)(&S0T[(dv0 + l15) * 136 + ko]);
          acc = MFMA(af, bfv, acc);
        }
        #pragma unroll
        for (int r = 0; r < 4; r++) {
          int t = r0 + trt + l4 * 4 + r;
          conv[(size_t)t * 8192 + 4096 + hv * 128 + dvh + dv0 + l15] = f2bf(acc[r]);
        }
      }
      float lamC = *(const float*)(vb + 256);
      const unsigned short* m2b = M2g + (size_t)bhc * 8192;
      #pragma unroll
      for (int dvt = 0; dvt < 4; dvt++) {
        f32x4 a = S[dvt];
        a[0] *= lamC; a[1] *= lamC; a[2] *= lamC; a[3] *= lamC;
        #pragma unroll
        for (int ks = 0; ks < 2; ks++) {
          int so = ks * 32 + l4 * 8;
          union { uint4 u4; bf16x8 h; } af;
          af.u4 = *(const uint4*)(m2b + (dkb + l15) * 64 + so);
          bf16x8 bfv = *(const bf16x8*)(&rhsT[(dvt * 16 + l15) * 72 + so]);
          a = MFMA(af.h, bfv, a);
        }
        S[dvt] = a;
      }
    }
    __syncthreads();   // B2
    #pragma unroll
    for (int dvt = 0; dvt < 4; dvt++)
      #pragma unroll
      for (int r = 0; r < 4; r++)
        S0T[(dvt * 16 + l15) * 136 + dkb + l4 * 4 + r] = f2bf(S[dvt][r]);
  }
}

// ---------------- gated RMSNorm in-place on o ----------------
__global__ __launch_bounds__(256) void rmsgate_kernel(unsigned short* __restrict__ conv,
                                                      const unsigned short* __restrict__ zg,
                                                      const float* __restrict__ nw) {
  int wid = blockIdx.x * 4 + (threadIdx.x >> 6);
  int lane = threadIdx.x & 63;
  int row = wid >> 5, hv = wid & 31;
  unsigned short* op = conv + (size_t)row * 8192 + 4096 + hv * 128;
  float o0 = bf2f(op[lane]), o1 = bf2f(op[64 + lane]);
  float ss = o0 * o0 + o1 * o1;
  #pragma unroll
  for (int m = 1; m < 64; m <<= 1) ss += __shfl_xor(ss, m);
  float r = rsqrtf(ss * (1.f / 128.f) + 1e-6f);
  const unsigned short* zp = zg + (size_t)row * 4096 + hv * 128;
  float g0 = bf2f(zp[lane]), g1 = bf2f(zp[64 + lane]);
  g0 = g0 / (1.f + expf(-g0));
  g1 = g1 / (1.f + expf(-g1));
  op[lane] = f2bf(o0 * r * g0 * nw[lane]);
  op[64 + lane] = f2bf(o1 * r * g1 * nw[64 + lane]);
}

extern "C" void kernel_launch(void* const* d_in, const int* in_sizes, int n_in,
                              void* d_out, int out_size, void* d_ws, size_t ws_size,
                              hipStream_t stream) {
  (void)in_sizes; (void)n_in; (void)out_size;
  const float* x       = (const float*)d_in[0];
  const float* W_qkv   = (const float*)d_in[1];
  const float* W_z     = (const float*)d_in[2];
  const float* W_b     = (const float*)d_in[3];
  const float* W_a     = (const float*)d_in[4];
  const float* conv_w  = (const float*)d_in[5];
  const float* dt_bias = (const float*)d_in[6];
  const float* A_log   = (const float*)d_in[7];
  const float* nw      = (const float*)d_in[8];
  const float* W_out   = (const float*)d_in[9];
  float* out = (float*)d_out;

  const size_t NEED = 169115648ULL;
  if (ws_size < NEED) return;

  char* ws = (char*)d_ws;
  // slot0 @0 (64MB): WbaT(256KB) -> qkv_bf -> {M1g, M2g} -> WoutT
  unsigned short* WbaT   = (unsigned short*)(ws + 0);
  unsigned short* qkv_bf = (unsigned short*)(ws + 0);
  unsigned short* M1g    = (unsigned short*)(ws + 0);
  unsigned short* M2g    = (unsigned short*)(ws + 16777216);
  unsigned short* WoutT  = (unsigned short*)(ws + 0);
  // zg @64MB (32MB)
  unsigned short* zg     = (unsigned short*)(ws + 67108864);
  // slot2 @96MB (64MB): {WallT 48MB, x_bf 16MB} -> convb
  unsigned short* WallT  = (unsigned short*)(ws + 100663296);
  unsigned short* x_bf   = (unsigned short*)(ws + 100663296 + 50331648);
  unsigned short* convb  = (unsigned short*)(ws + 100663296);
  // tail @160MB
  unsigned short* betab  = (unsigned short*)(ws + 167772160);
  float* gbuf            = (float*)(ws + 168034304);
  unsigned char* vecs    = (unsigned char*)(ws + 168558592);

  const int M = MROWS;

  transpose_multi<<<32896, 256, 0, stream>>>(W_qkv, W_z, W_b, W_a, x, WallT, WbaT, x_bf);

  gemm_ba<<<dim3(1, M / 128), 256, 0, stream>>>(x_bf, 2048, WbaT, 2048,
                                                A_log, dt_bias, betab, gbuf, M, 2048);

  gemm8p<1><<<768, 512, 0, stream>>>(x_bf, 2048, WallT, 2048,
                                     qkv_bf, 8192, 8192, zg, 4096, M, 12288, 2048);

  conv_kernel<<<dim3(64, 64, 2), 256, 0, stream>>>(qkv_bf, conv_w, convb);

  prep_kernel<<<dim3(32, 64), 256, 0, stream>>>(convb, gbuf, betab, M1g, M2g, vecs);

  seq_kernel<<<dim3(2, 64), 512, 0, stream>>>(convb, M1g, M2g, vecs, betab);

  rmsgate_kernel<<<32768, 256, 0, stream>>>(convb, zg, nw);

  transpose_f2b<<<dim3(2048 / 32, 4096 / 32), 256, 0, stream>>>(W_out, WoutT, 4096, 2048);
  gemm256<0, 128><<<256, 512, 0, stream>>>(convb + 4096, 8192, WoutT, 4096, out, 2048, M, 2048, 4096);
}

// Round 19
// 593.487 us; speedup vs baseline: 1.0011x; 1.0011x over previous
//
#include <hip/hip_runtime.h>

// Qwen3.5 GatedDeltaNet fwd on gfx950 — chunked delta-rule + 8-phase 256^2 GEMM.
// B=2 T=2048 HID=2048 HK=16 HV=32 DK=DV=128 KW=4, chunk C=64 (32 chunks).
// R19: gemm256 (GEMM3) ported to sync-before-MFMA schedule — frags to regs,
// lgkmcnt(0)+barrier, STAGE(t+2), reg-only MFMA, vmcnt(IS)+barrier.

#define T_LEN 2048
#define MROWS 4096

typedef __bf16 bf16x8 __attribute__((ext_vector_type(8)));
typedef float f32x4 __attribute__((ext_vector_type(4)));

#define MFMA(a, b, c) __builtin_amdgcn_mfma_f32_16x16x32_bf16((a), (b), (c), 0, 0, 0)

__device__ __forceinline__ unsigned short f2bf(float f) {
  unsigned int u = __float_as_uint(f);
  unsigned int r = (u + 0x7fffu + ((u >> 16) & 1u)) >> 16;
  return (unsigned short)r;
}
__device__ __forceinline__ float bf2f(unsigned short u) {
  return __uint_as_float(((unsigned int)u) << 16);
}
__device__ __forceinline__ void gload_lds16(const void* g, void* l) {
  __builtin_amdgcn_global_load_lds(
      (const __attribute__((address_space(1))) unsigned int*)g,
      (__attribute__((address_space(3))) unsigned int*)l, 16, 0, 0);
}

// ---------------- transpose f32 [R,C] -> bf16 [C,R] (W_out) ----------------
__global__ __launch_bounds__(256) void transpose_f2b(const float* __restrict__ src,
                                                     unsigned short* __restrict__ dst,
                                                     int R, int C) {
  __shared__ float tile[32][33];
  int tx = threadIdx.x & 31, ty = threadIdx.x >> 5;
  int c0 = blockIdx.x * 32, r0 = blockIdx.y * 32;
  #pragma unroll
  for (int i = ty; i < 32; i += 8)
    tile[i][tx] = src[(size_t)(r0 + i) * C + c0 + tx];
  __syncthreads();
  #pragma unroll
  for (int i = ty; i < 32; i += 8)
    dst[(size_t)(c0 + i) * R + r0 + tx] = f2bf(tile[tx][i]);
}

// ------- merged: W_qkv/W_z/W_b/W_a transposes + x f32->bf16 convert -------
__global__ __launch_bounds__(256) void transpose_multi(const float* __restrict__ Wqkv,
                                                       const float* __restrict__ Wz,
                                                       const float* __restrict__ Wb,
                                                       const float* __restrict__ Wa,
                                                       const float* __restrict__ x,
                                                       unsigned short* __restrict__ WallT,
                                                       unsigned short* __restrict__ WbaT,
                                                       unsigned short* __restrict__ x_bf) {
  int bid = blockIdx.x;
  if (bid >= 24704) {   // x convert: 8192 blocks over 2,097,152 float4
    int i = (bid - 24704) * 256 + threadIdx.x;
    float4 v = ((const float4*)x)[i];
    ushort4 o;
    o.x = f2bf(v.x); o.y = f2bf(v.y); o.z = f2bf(v.z); o.w = f2bf(v.w);
    ((ushort4*)x_bf)[i] = o;
    return;
  }
  const float* src; unsigned short* dst; int C, cx, ry;
  if (bid < 16384)                 { src = Wqkv; dst = WallT; C = 8192; cx = bid & 255; ry = bid >> 8; }
  else if ((bid -= 16384) < 8192)  { src = Wz; dst = WallT + (size_t)8192 * 2048; C = 4096; cx = bid & 127; ry = bid >> 7; }
  else if ((bid -= 8192) < 64)     { src = Wb; dst = WbaT; C = 32; cx = 0; ry = bid; }
  else { bid -= 64;                  src = Wa; dst = WbaT + (size_t)32 * 2048; C = 32; cx = 0; ry = bid; }
  const int R = 2048;
  __shared__ float tile[32][33];
  int tx = threadIdx.x & 31, ty = threadIdx.x >> 5;
  int c0 = cx * 32, r0 = ry * 32;
  #pragma unroll
  for (int i = ty; i < 32; i += 8)
    if (c0 + tx < C) tile[i][tx] = src[(size_t)(r0 + i) * C + c0 + tx];
  __syncthreads();
  #pragma unroll
  for (int i = ty; i < 32; i += 8)
    if (c0 + i < C) dst[(size_t)(c0 + i) * R + r0 + tx] = f2bf(tile[tx][i]);
}

// ============ 8-phase 256^2 GEMM with split output (cols<Nsplit -> Cv, else Cv2) ============
template <int OUTBF>
__global__ __launch_bounds__(512, 2) void gemm8p(const unsigned short* __restrict__ A, int lda,
                                                 const unsigned short* __restrict__ Bt, int ldb,
                                                 void* __restrict__ Cv, int ldc,
                                                 int Nsplit, void* __restrict__ Cv2, int ldc2,
                                                 int M, int N, int K) {
  __shared__ unsigned short lds[65536];   // 128 KB

  const int mtiles = M >> 8;
  const int nwg = gridDim.x, orig = blockIdx.x;
  const int q = nwg >> 3, r = nwg & 7;
  const int xcd = orig & 7, idx = orig >> 3;
  const int swz = (xcd < r ? xcd * (q + 1) : r * (q + 1) + (xcd - r) * q) + idx;
  const int m0 = (swz % mtiles) * 256;
  const int n0 = (swz / mtiles) * 256;

  const int tid = threadIdx.x, lane = tid & 63, wv = tid >> 6;
  const int wm = wv >> 2, wn = wv & 3;
  const int l15 = lane & 15, l4 = lane >> 4;

  f32x4 acc[8][4];
  #pragma unroll
  for (int i = 0; i < 8; i++)
    #pragma unroll
    for (int j = 0; j < 4; j++) acc[i][j] = f32x4{0.f, 0.f, 0.f, 0.f};

  const int NT = K >> 6;

  auto SHALF = [&](int t, int op, int h) {
    unsigned short* base = lds + (t & 1) * 32768 + op * 16384 + h * 8192;
    const unsigned short* G = op ? Bt : A;
    const int ld = op ? ldb : lda;
    const int r0g = (op ? n0 : m0) + h * 128;
    const int k0 = t << 6;
    #pragma unroll
    for (int is = 0; is < 2; is++) {
      int ow = is * 8192 + wv * 1024;
      int o = ow + lane * 16;
      int row = o >> 7, colB = o & 127;
      int scol = colB ^ ((row & 7) << 4);
      gload_lds16(G + (size_t)(r0g + row) * ld + k0 + (scol >> 1), base + (ow >> 1));
    }
  };

  bf16x8 aF[4][2], bF[2][2], bF0[2][2];
  auto RD_A = [&](int t, int qm) {
    const unsigned short* base = lds + (t & 1) * 32768 + qm * 8192;
    #pragma unroll
    for (int mi = 0; mi < 4; mi++) {
      int ra = wm * 64 + mi * 16 + l15;
      int sw = (ra & 7) << 4;
      #pragma unroll
      for (int kh = 0; kh < 2; kh++) {
        int colB = kh * 64 + l4 * 16;
        aF[mi][kh] = *(const bf16x8*)(base + ra * 64 + ((colB ^ sw) >> 1));
      }
    }
  };
  auto RD_B = [&](int t, int qn, bf16x8 (&bdst)[2][2]) {
    const unsigned short* base = lds + (t & 1) * 32768 + 16384 + qn * 8192;
    #pragma unroll
    for (int ni = 0; ni < 2; ni++) {
      int rb = wn * 32 + ni * 16 + l15;
      int sw = (rb & 7) << 4;
      #pragma unroll
      for (int kh = 0; kh < 2; kh++) {
        int colB = kh * 64 + l4 * 16;
        bdst[ni][kh] = *(const bf16x8*)(base + rb * 64 + ((colB ^ sw) >> 1));
      }
    }
  };
  auto COMPUTE = [&](int qm, int qn, const bf16x8 (&bsrc)[2][2]) {
    __builtin_amdgcn_s_setprio(1);
    #pragma unroll
    for (int mi = 0; mi < 4; mi++)
      #pragma unroll
      for (int ni = 0; ni < 2; ni++)
        #pragma unroll
        for (int kh = 0; kh < 2; kh++)
          acc[qm * 4 + mi][qn * 2 + ni] =
              MFMA(aF[mi][kh], bsrc[ni][kh], acc[qm * 4 + mi][qn * 2 + ni]);
    __builtin_amdgcn_s_setprio(0);
  };
  auto SBAR = [&]() {
    __builtin_amdgcn_sched_barrier(0);
    __builtin_amdgcn_s_barrier();
    __builtin_amdgcn_sched_barrier(0);
  };

  // prologue: stage tile0 fully, publish
  SHALF(0, 0, 0); SHALF(0, 1, 0); SHALF(0, 1, 1); SHALF(0, 0, 1);
  asm volatile("s_waitcnt vmcnt(0)" ::: "memory");
  SBAR();

  for (int t = 0; t < NT; t++) {
    const bool lastT = (t + 1 >= NT);
    // ph0: reads + staging first, sync (completes B1[t]), then MFMA
    RD_A(t, 0); RD_B(t, 0, bF0);
    if (!lastT) {
      SHALF(t + 1, 0, 0);
      asm volatile("s_waitcnt vmcnt(4)" ::: "memory");
    } else {
      asm volatile("s_waitcnt vmcnt(2)" ::: "memory");
    }
    SBAR();
    COMPUTE(0, 0, bF0);
    // ph1: sync completes A1[t]
    RD_B(t, 1, bF);
    if (!lastT) {
      SHALF(t + 1, 1, 0);
      asm volatile("s_waitcnt vmcnt(4)" ::: "memory");
    } else {
      asm volatile("s_waitcnt vmcnt(0)" ::: "memory");
    }
    SBAR();
    COMPUTE(0, 1, bF);
    // ph2: no sync needed (A1[t] published at ph1 sync)
    RD_A(t, 1);
    if (!lastT) SHALF(t + 1, 1, 1);
    COMPUTE(1, 1, bF);
    // ph3: boundary sync BEFORE the reg-only MFMA cluster (completes A0,B0[t+1])
    if (!lastT) {
      SHALF(t + 1, 0, 1);
      asm volatile("s_waitcnt vmcnt(4)" ::: "memory");
      SBAR();
    }
    COMPUTE(1, 0, bF0);
  }

  #pragma unroll
  for (int i = 0; i < 8; i++) {
    int grow = m0 + (i >> 2) * 128 + wm * 64 + (i & 3) * 16 + l4 * 4;
    #pragma unroll
    for (int j = 0; j < 4; j++) {
      int gcol = n0 + (j >> 1) * 128 + wn * 32 + (j & 1) * 16 + l15;
      if (OUTBF) {
        if (gcol < Nsplit) {
          unsigned short* cp = (unsigned short*)Cv + (size_t)grow * ldc + gcol;
          #pragma unroll
          for (int rr = 0; rr < 4; rr++) cp[(size_t)rr * ldc] = f2bf(acc[i][j][rr]);
        } else {
          unsigned short* cp = (unsigned short*)Cv2 + (size_t)grow * ldc2 + (gcol - Nsplit);
          #pragma unroll
          for (int rr = 0; rr < 4; rr++) cp[(size_t)rr * ldc2] = f2bf(acc[i][j][rr]);
        }
      } else {
        float* cp = (float*)Cv + (size_t)grow * ldc + gcol;
        #pragma unroll
        for (int rr = 0; rr < 4; rr++) cp[(size_t)rr * ldc] = acc[i][j][rr];
      }
    }
  }
}

// ===== 256xBN GEMM (GEMM3), sync-before-MFMA schedule, frags in registers =====
template <int OUTBF, int BN>
__global__ __launch_bounds__(512, 2) void gemm256(const unsigned short* __restrict__ A, int lda,
                                                  const unsigned short* __restrict__ Bt, int ldb,
                                                  void* __restrict__ Cv, int ldc,
                                                  int M, int N, int K) {
  constexpr int BUFSZ = 16384 + BN * 64;
  constexpr int BISS = BN / 64;
  constexpr int IS = 4 + BISS;
  constexpr int WMv = (BN == 256) ? 2 : 4;
  constexpr int MSUB = 256 / (WMv * 16);
  constexpr int MSPAN = 256 / WMv;

  __shared__ unsigned short lds[2 * BUFSZ];

  const int mtiles = M >> 8;
  const int nwg = gridDim.x;
  const int orig = blockIdx.x;
  const int q = nwg >> 3, r = nwg & 7;
  const int xcd = orig & 7, idx = orig >> 3;
  const int swz = (xcd < r ? xcd * (q + 1) : r * (q + 1) + (xcd - r) * q) + idx;
  const int m0 = (swz % mtiles) * 256;
  const int n0 = (swz / mtiles) * BN;

  const int tid = threadIdx.x, lane = tid & 63, wv = tid >> 6;
  const int wm = (BN == 256) ? (wv >> 2) : (wv >> 1);
  const int wn = (BN == 256) ? (wv & 3) : (wv & 1);
  const int l15 = lane & 15, l4 = lane >> 4;

  f32x4 acc[MSUB][4];
  #pragma unroll
  for (int i = 0; i < MSUB; i++)
    #pragma unroll
    for (int j = 0; j < 4; j++) acc[i][j] = f32x4{0.f, 0.f, 0.f, 0.f};

  const int NT = K >> 6;

  auto STAGE = [&](int kt) {
    unsigned short* base = lds + (kt & 1) * BUFSZ;
    const int k0 = kt << 6;
    #pragma unroll
    for (int is = 0; is < 4; is++) {
      int ow = is * 8192 + wv * 1024;
      int o = ow + lane * 16;
      int row = o >> 7, colB = o & 127;
      int scol = colB ^ ((row & 7) << 4);
      gload_lds16(A + (size_t)(m0 + row) * lda + k0 + (scol >> 1), base + (ow >> 1));
    }
    #pragma unroll
    for (int is = 0; is < BISS; is++) {
      int ow = is * 8192 + wv * 1024;
      int o = ow + lane * 16;
      int row = o >> 7, colB = o & 127;
      int scol = colB ^ ((row & 7) << 4);
      gload_lds16(Bt + (size_t)(n0 + row) * ldb + k0 + (scol >> 1), base + 16384 + (ow >> 1));
    }
  };
  auto SBAR = [&]() {
    __builtin_amdgcn_sched_barrier(0);
    __builtin_amdgcn_s_barrier();
    __builtin_amdgcn_sched_barrier(0);
  };

  STAGE(0);
  if (NT > 1) {
    STAGE(1);
    asm volatile("s_waitcnt vmcnt(%0)" :: "i"(IS) : "memory");
  } else {
    asm volatile("s_waitcnt vmcnt(0)" ::: "memory");
  }
  SBAR();

  for (int t = 0; t < NT; t++) {
    const unsigned short* Abuf = lds + (t & 1) * BUFSZ;
    const unsigned short* Bbuf = Abuf + 16384;
    // read all fragments of tile t into registers
    bf16x8 bF[4][2], aFr[MSUB][2];
    #pragma unroll
    for (int n = 0; n < 4; n++) {
      int rb = wn * 64 + n * 16 + l15;
      int sw = (rb & 7) << 4;
      #pragma unroll
      for (int ks = 0; ks < 2; ks++) {
        int colB = (ks * 32 + l4 * 8) * 2;
        bF[n][ks] = *(const bf16x8*)(Bbuf + rb * 64 + ((colB ^ sw) >> 1));
      }
    }
    #pragma unroll
    for (int m = 0; m < MSUB; m++) {
      int ra = wm * MSPAN + m * 16 + l15;
      int sw = (ra & 7) << 4;
      int c0b = l4 * 16;
      aFr[m][0] = *(const bf16x8*)(Abuf + ra * 64 + ((c0b ^ sw) >> 1));
      aFr[m][1] = *(const bf16x8*)(Abuf + ra * 64 + (((64 + c0b) ^ sw) >> 1));
    }
    // all reads complete (same-wave + cross-wave) before overwriting buf[t&1]
    asm volatile("s_waitcnt lgkmcnt(0)" ::: "memory");
    SBAR();
    if (t + 2 < NT) STAGE(t + 2);
    __builtin_amdgcn_s_setprio(1);
    #pragma unroll
    for (int m = 0; m < MSUB; m++)
      #pragma unroll
      for (int n = 0; n < 4; n++) {
        acc[m][n] = MFMA(aFr[m][0], bF[n][0], acc[m][n]);
        acc[m][n] = MFMA(aFr[m][1], bF[n][1], acc[m][n]);
      }
    __builtin_amdgcn_s_setprio(0);
    if (t + 1 < NT) {
      if (t + 2 < NT) asm volatile("s_waitcnt vmcnt(%0)" :: "i"(IS) : "memory");
      else            asm volatile("s_waitcnt vmcnt(0)" ::: "memory");
      SBAR();
    }
  }

  #pragma unroll
  for (int m = 0; m < MSUB; m++) {
    int grow = m0 + wm * MSPAN + m * 16 + l4 * 4;
    #pragma unroll
    for (int n = 0; n < 4; n++) {
      int gcol = n0 + wn * 64 + n * 16 + l15;
      if (OUTBF) {
        unsigned short* cp = (unsigned short*)Cv + (size_t)grow * ldc + gcol;
        #pragma unroll
        for (int rr = 0; rr < 4; rr++) cp[(size_t)rr * ldc] = f2bf(acc[m][n][rr]);
      } else {
        float* cp = (float*)Cv + (size_t)grow * ldc + gcol;
        #pragma unroll
        for (int rr = 0; rr < 4; rr++) cp[(size_t)rr * ldc] = acc[m][n][rr];
      }
    }
  }
}

// ------- ba-GEMM (128^2) with fused beta/g epilogue -------
__global__ __launch_bounds__(256) void gemm_ba(const unsigned short* __restrict__ A, int lda,
                                               const unsigned short* __restrict__ Bt, int ldb,
                                               const float* __restrict__ A_log,
                                               const float* __restrict__ dt_bias,
                                               unsigned short* __restrict__ betab,
                                               float* __restrict__ g,
                                               int M, int K) {
  __shared__ unsigned short As[128 * 64];
  __shared__ unsigned short Bs[128 * 64];
  const int tid = threadIdx.x, lane = tid & 63, wv = tid >> 6;
  const int wr = wv >> 1, wc = wv & 1;
  const int m0 = blockIdx.y * 128;
  const int lrow8 = lane >> 3;
  const int lk8 = (lane & 7) * 8;

  f32x4 acc[4][4];
  #pragma unroll
  for (int i = 0; i < 4; i++)
    #pragma unroll
    for (int j = 0; j < 4; j++) acc[i][j] = f32x4{0.f, 0.f, 0.f, 0.f};

  for (int k0 = 0; k0 < K; k0 += 64) {
    #pragma unroll
    for (int j = 0; j < 4; ++j) {
      int chunk = j * 4 + wv;
      int r = chunk * 8 + lrow8;
      gload_lds16(A + (size_t)(m0 + r) * lda + k0 + lk8, (void*)(As + chunk * 512));
      gload_lds16(Bt + (size_t)r * ldb + k0 + lk8, (void*)(Bs + chunk * 512));
    }
    __syncthreads();
    #pragma unroll
    for (int half = 0; half < 2; ++half) {
      int ko = half * 32 + (lane >> 4) * 8;
      bf16x8 af[4], bfr[4];
      #pragma unroll
      for (int i = 0; i < 4; i++) {
        int ra = wr * 64 + i * 16 + (lane & 15);
        af[i] = *(const bf16x8*)(As + ra * 64 + ko);
        int rb = wc * 64 + i * 16 + (lane & 15);
        bfr[i] = *(const bf16x8*)(Bs + rb * 64 + ko);
      }
      #pragma unroll
      for (int i = 0; i < 4; i++)
        #pragma unroll
        for (int j = 0; j < 4; j++)
          acc[i][j] = MFMA(af[i], bfr[j], acc[i][j]);
    }
    __syncthreads();
  }
  int cr4 = (lane >> 4) * 4;
  int cc = lane & 15;
  #pragma unroll
  for (int i = 0; i < 4; i++) {
    int row = m0 + wr * 64 + i * 16 + cr4;
    #pragma unroll
    for (int j = 0; j < 4; j++) {
      int col = wc * 64 + j * 16 + cc;
      if (col < 64) {
        #pragma unroll
        for (int r = 0; r < 4; r++) {
          int erow = row + r;
          float a = acc[i][j][r];
          if (col < 32) {
            betab[(size_t)erow * 32 + col] = f2bf(1.f / (1.f + expf(-a)));
          } else {
            int hvv = col - 32;
            float xg = a + dt_bias[hvv];
            float sp = (xg > 20.f) ? xg : log1pf(expf(xg));
            g[(size_t)erow * 32 + hvv] = -expf(A_log[hvv]) * sp;
          }
        }
      }
    }
  }
}

// ------- conv4 + SiLU + q/k l2norm -------
__global__ __launch_bounds__(256) void conv_kernel(const unsigned short* __restrict__ qkv,
                                                   const float* __restrict__ conv_w,
                                                   unsigned short* __restrict__ out) {
  const int seg = blockIdx.x, tt = blockIdx.y, b = blockIdx.z;
  const int tid = threadIdx.x;
  const int c0 = seg * 128;
  const bool isq = seg < 16;
  int scb;
  if (isq) scb = seg * 512;
  else if (seg < 32) scb = (seg - 16) * 512 + 128;
  else scb = ((seg - 32) >> 1) * 512 + 256 + ((seg - 32) & 1) * 128;

  __shared__ unsigned short raw[35][136];
  __shared__ float cw[4][132];

  for (int i = tid; i < 512; i += 256) {
    int cl = i >> 2, tap = i & 3;
    cw[tap][cl] = conv_w[(size_t)(c0 + cl) * 4 + tap];
  }
  const int t0 = tt * 32;
  for (int i = tid; i < 560; i += 256) {
    int row = i >> 4, col = (i & 15) * 8;
    int gt = t0 - 3 + row;
    uint4 v = make_uint4(0u, 0u, 0u, 0u);
    if (gt >= 0) v = *(const uint4*)(qkv + (size_t)(b * T_LEN + gt) * 8192 + scb + col);
    *(uint4*)(&raw[row][col]) = v;
  }
  __syncthreads();
  const int s = tid >> 3, dg = tid & 7;
  union RawU { uint4 v[2]; unsigned short h[16]; };
  RawU u[4];
  #pragma unroll
  for (int i = 0; i < 4; i++) {
    const uint4* p = (const uint4*)&raw[s + i][dg * 16];
    u[i].v[0] = p[0]; u[i].v[1] = p[1];
  }
  float vals[16]; float ss = 0.f;
  #pragma unroll
  for (int j = 0; j < 16; j++) {
    float a = 0.f;
    #pragma unroll
    for (int i = 0; i < 4; i++) a = fmaf(cw[i][dg * 16 + j], bf2f(u[i].h[j]), a);
    a = a / (1.f + expf(-a));
    vals[j] = a; ss += a * a;
  }
  if (seg < 32) {
    ss += __shfl_xor(ss, 1); ss += __shfl_xor(ss, 2); ss += __shfl_xor(ss, 4);
    float sc = rsqrtf(ss + 1e-6f);
    if (isq) sc *= 0.08838834764831845f;
    #pragma unroll
    for (int j = 0; j < 16; j++) vals[j] *= sc;
  }
  union { uint4 v[2]; unsigned short h[16]; } ov;
  #pragma unroll
  for (int j = 0; j < 16; j++) ov.h[j] = f2bf(vals[j]);
  unsigned short* op = out + (size_t)(b * T_LEN + t0 + s) * 8192 + c0 + dg * 16;
  *(uint4*)(op) = ov.v[0];
  *(uint4*)(op + 8) = ov.v[1];
}

// ---------------- prep: per chunk-head precompute M1, M2, vecs ----------------
__global__ __launch_bounds__(256) void prep_kernel(const unsigned short* __restrict__ conv,
                                                   const float* __restrict__ g,
                                                   const unsigned short* __restrict__ betab,
                                                   unsigned short* __restrict__ M1g,
                                                   unsigned short* __restrict__ M2g,
                                                   unsigned char* __restrict__ vecs) {
  const int c = blockIdx.x, bh = blockIdx.y;
  const int b = bh >> 5, hv = bh & 31, hk = hv >> 1;
  const int bhc = bh * 32 + c;
  const int tid = threadIdx.x, lane = tid & 63, wv = tid >> 6;
  const int r0 = b * T_LEN + c * 64;
  const int l15 = lane & 15, l4 = lane >> 4;

  __shared__ unsigned short Kb[128 * 72];
  __shared__ unsigned short QbX[64 * 136];
  __shared__ unsigned short Lbf[64 * 72];
  __shared__ unsigned short Pb[64 * 72];
  __shared__ unsigned short WT[3 * 16 * 40];
  __shared__ float Gs[64], SCs[64], BLs[64];

  unsigned short* Qb = QbX;
  unsigned short* XTb = QbX;
  unsigned short* Xdrow = QbX + 4608;

  if (wv == 0) {
    float gt = g[(size_t)(r0 + lane) * 32 + hv];
    #pragma unroll
    for (int d = 1; d < 64; d <<= 1) {
      float o = __shfl_up(gt, (unsigned)d, 64);
      if (lane >= d) gt += o;
    }
    float GC = __shfl(gt, 63, 64);
    float lam = expf(gt);
    float beta = bf2f(betab[(size_t)(r0 + lane) * 32 + hv]);
    Gs[lane] = gt;
    SCs[lane] = expf(GC - gt);
    BLs[lane] = beta;
    unsigned short* vb16 = (unsigned short*)(vecs + (size_t)bhc * 272);
    vb16[lane] = f2bf(beta * lam);
    vb16[64 + lane] = f2bf(lam);
    if (lane == 0) *(float*)(vecs + (size_t)bhc * 272 + 256) = expf(GC);
  }
  const unsigned short* Kg = conv + (size_t)r0 * 8192 + 2048 + hk * 128;
  const unsigned short* Qg = conv + (size_t)r0 * 8192 + hk * 128;
  for (int u = tid; u < 1024; u += 256) {
    int row = u >> 4, col = (u & 15) * 8;
    *(uint4*)(&Kb[row * 136 + col]) = *(const uint4*)(Kg + (size_t)row * 8192 + col);
    *(uint4*)(&Qb[row * 136 + col]) = *(const uint4*)(Qg + (size_t)row * 8192 + col);
  }
  __syncthreads();

  {
    f32x4 akk[4], aqk[4];
    #pragma unroll
    for (int st = 0; st < 4; st++) { akk[st] = f32x4{0,0,0,0}; aqk[st] = f32x4{0,0,0,0}; }
    int trow = wv * 16 + l15;
    int klo = l4 * 8;
    #pragma unroll
    for (int ks = 0; ks < 4; ks++) {
      int ko = ks * 32 + klo;
      bf16x8 ak = *(const bf16x8*)(&Kb[trow * 136 + ko]);
      bf16x8 aq = *(const bf16x8*)(&Qb[trow * 136 + ko]);
      #pragma unroll
      for (int st = 0; st < 4; st++) {
        bf16x8 bk = *(const bf16x8*)(&Kb[(st * 16 + l15) * 136 + ko]);
        akk[st] = MFMA(ak, bk, akk[st]);
        aqk[st] = MFMA(aq, bk, aqk[st]);
      }
    }
    int orow = wv * 16 + l4 * 4;
    int oc = l15;
    #pragma unroll
    for (int st = 0; st < 4; st++)
      #pragma unroll
      for (int r = 0; r < 4; r++) {
        int t = orow + r, ssv = st * 16 + oc;
        float e = expf(fminf(Gs[t] - Gs[ssv], 0.f));
        Lbf[t * 72 + ssv] = f2bf((ssv < t) ? BLs[t] * e * akk[st][r] : 0.f);
        Pb[t * 72 + ssv] = f2bf((ssv <= t) ? e * aqk[st][r] : 0.f);
      }
  }
  __syncthreads();

  unsigned short ktv[32];
  {
    int dk = tid >> 1, tb = (tid & 1) * 32;
    #pragma unroll
    for (int i = 0; i < 32; i++)
      ktv[i] = f2bf(bf2f(Kb[(tb + i) * 136 + dk]) * SCs[tb + i]);
    for (int u = tid; u < 896; u += 256) {
      *(uint4*)(&QbX[u * 8]) = make_uint4(0u, 0u, 0u, 0u);
    }
    for (int u = tid; u < 240; u += 256) {
      *(uint4*)(&WT[u * 8]) = make_uint4(0u, 0u, 0u, 0u);
    }
  }
  __syncthreads();

  {
    int dk = tid >> 1, tb = (tid & 1) * 32;
    #pragma unroll
    for (int i = 0; i < 32; i++) Kb[dk * 72 + tb + i] = ktv[i];
  }
  {
    const int w16 = wv * 16;
    const int cc = l15;
    float xr[16];
    #pragma unroll
    for (int t = 0; t < 16; t++) {
      float acc = (cc == t) ? 1.f : 0.f;
      union { uint4 v[2]; unsigned short h[16]; } rw;
      const uint4* p = (const uint4*)(&Lbf[(w16 + t) * 72 + w16]);
      rw.v[0] = p[0]; rw.v[1] = p[1];
      #pragma unroll
      for (int s = 0; s < 16; s++) {
        if (s < t) acc = fmaf(-bf2f(rw.h[s]), xr[s], acc);
      }
      xr[t] = acc;
    }
    if (lane < 16) {
      #pragma unroll
      for (int t = 0; t < 16; t++) {
        unsigned short v = f2bf(xr[t]);
        XTb[(w16 + cc) * 72 + w16 + t] = v;
        Xdrow[wv * 640 + t * 40 + cc] = v;
      }
    }
  }
  __syncthreads();

  if (wv < 3) {
    const int j = wv;
    for (int i = j + 1; i < 4; i++) {
      f32x4 w_ = f32x4{0.f, 0.f, 0.f, 0.f};
      #pragma unroll
      for (int ks = 0; ks < 2; ks++) {
        int so = ks * 32 + l4 * 8;
        bf16x8 af = *(const bf16x8*)(&Lbf[(i * 16 + l15) * 72 + so]);
        bf16x8 bfv = *(const bf16x8*)(&XTb[(j * 16 + l15) * 72 + so]);
        w_ = MFMA(af, bfv, w_);
      }
      #pragma unroll
      for (int r = 0; r < 4; r++)
        WT[j * 640 + l15 * 40 + l4 * 4 + r] = f2bf(-w_[r]);
      f32x4 xij = f32x4{0.f, 0.f, 0.f, 0.f};
      {
        bf16x8 af = *(const bf16x8*)(&Xdrow[i * 640 + l15 * 40 + l4 * 8]);
        bf16x8 bfv = *(const bf16x8*)(&WT[j * 640 + l15 * 40 + l4 * 8]);
        xij = MFMA(af, bfv, xij);
      }
      #pragma unroll
      for (int r = 0; r < 4; r++)
        XTb[(j * 16 + l15) * 72 + i * 16 + l4 * 4 + r] = f2bf(xij[r]);
    }
  }
  __syncthreads();

  for (int tt = wv * 12; tt < wv * 12 + 12; tt++) {
    f32x4 acc = f32x4{0, 0, 0, 0};
    const unsigned short* Abase;
    int mrow, jc;
    if (tt < 16) { mrow = (tt >> 2) * 16; jc = (tt & 3) * 16; Abase = Pb + mrow * 72; }
    else { int i2 = tt - 16; mrow = (i2 >> 2) * 16; jc = (i2 & 3) * 16; Abase = Kb + mrow * 72; }
    #pragma unroll
    for (int ks = 0; ks < 2; ks++) {
      int so = ks * 32 + l4 * 8;
      bf16x8 af = *(const bf16x8*)(Abase + l15 * 72 + so);
      bf16x8 bfv = *(const bf16x8*)(&XTb[(jc + l15) * 72 + so]);
      acc = MFMA(af, bfv, acc);
    }
    int ro = mrow + l4 * 4, co = jc + l15;
    if (tt < 16) {
      #pragma unroll
      for (int r = 0; r < 4; r++)
        M1g[(size_t)bhc * 4096 + (ro + r) * 64 + co] = f2bf(acc[r]);
    } else {
      #pragma unroll
      for (int r = 0; r < 4; r++)
        M2g[(size_t)bhc * 8192 + (ro + r) * 64 + co] = f2bf(acc[r]);
    }
  }
}

// ---------------- sequential chunk recurrence ----------------
// grid (2 dv-halves, 64 bh); block 512 (8 waves). S-state in registers.
__global__ __launch_bounds__(512) void seq_kernel(unsigned short* __restrict__ conv,
                                                  const unsigned short* __restrict__ M1g,
                                                  const unsigned short* __restrict__ M2g,
                                                  const unsigned char* __restrict__ vecs,
                                                  const unsigned short* __restrict__ betab) {
  const int dvh = blockIdx.x * 64;
  const int bh = blockIdx.y;
  const int b = bh >> 5, hv = bh & 31, hk = hv >> 1;
  const int tid = threadIdx.x, lane = tid & 63, wv = tid >> 6;
  const int l15 = lane & 15, l4 = lane >> 4;

  __shared__ unsigned short Kb[64 * 136], Qb[64 * 136];
  __shared__ unsigned short Vb[64 * 72];
  __shared__ unsigned short S0T[64 * 136];
  __shared__ unsigned short rhsT[64 * 72];
  __shared__ unsigned short bts[64];

  f32x4 S[4];
  #pragma unroll
  for (int i = 0; i < 4; i++) S[i] = f32x4{0.f, 0.f, 0.f, 0.f};

  for (int i = tid; i < 1088; i += 512) *(uint4*)(&S0T[i * 8]) = make_uint4(0u, 0u, 0u, 0u);
  __syncthreads();

  const int trt = (wv >> 1) * 16;
  const int dsb = (wv & 1) * 32;
  const int dkb = wv * 16;

  for (int c = 0; c < 32; c++) {
    const int r0 = b * T_LEN + c * 64;
    const int bhc = bh * 32 + c;
    const unsigned char* vb = vecs + (size_t)bhc * 272;
    const unsigned short* vb16 = (const unsigned short*)vb;
    #pragma unroll
    for (int j = 0; j < 2; j++) {
      int u = j * 512 + tid;
      int row = u >> 4, col = (u & 15) * 8;
      uint4 kv = *(const uint4*)(conv + (size_t)(r0 + row) * 8192 + 2048 + hk * 128 + col);
      uint4 qv = *(const uint4*)(conv + (size_t)(r0 + row) * 8192 + hk * 128 + col);
      *(uint4*)(&Kb[row * 136 + col]) = kv;
      float lam = bf2f(vb16[64 + row]);
      union { uint4 u4; unsigned short h[8]; } qq; qq.u4 = qv;
      #pragma unroll
      for (int e = 0; e < 8; e++) qq.h[e] = f2bf(bf2f(qq.h[e]) * lam);
      *(uint4*)(&Qb[row * 136 + col]) = qq.u4;
    }
    {
      int row = tid >> 3, col = (tid & 7) * 8;
      *(uint4*)(&Vb[row * 72 + col]) =
          *(const uint4*)(conv + (size_t)(r0 + row) * 8192 + 4096 + hv * 128 + dvh + col);
      if (tid < 64) bts[tid] = betab[(size_t)(r0 + tid) * 32 + hv];
    }
    __syncthreads();   // B0
    #pragma unroll
    for (int dt = 0; dt < 2; dt++) {
      int dv0 = dsb + dt * 16;
      f32x4 acc = f32x4{0, 0, 0, 0};
      #pragma unroll
      for (int ks = 0; ks < 4; ks++) {
        int ko = ks * 32 + l4 * 8;
        bf16x8 af = *(const bf16x8*)(&Kb[(trt + l15) * 136 + ko]);
        bf16x8 bfv = *(const bf16x8*)(&S0T[(dv0 + l15) * 136 + ko]);
        acc = MFMA(af, bfv, acc);
      }
      #pragma unroll
      for (int r = 0; r < 4; r++) {
        int tl = trt + l4 * 4 + r;
        float beta = bf2f(bts[tl]);
        float bl = bf2f(vb16[tl]);
        float vv = bf2f(Vb[tl * 72 + dv0 + l15]);
        rhsT[(dv0 + l15) * 72 + tl] = f2bf(beta * vv - bl * acc[r]);
      }
    }
    __syncthreads();   // B1
    {
      const unsigned short* m1b = M1g + (size_t)bhc * 4096;
      #pragma unroll
      for (int dt = 0; dt < 2; dt++) {
        int dv0 = dsb + dt * 16;
        f32x4 acc = f32x4{0, 0, 0, 0};
        #pragma unroll
        for (int ks = 0; ks < 2; ks++) {
          int so = ks * 32 + l4 * 8;
          union { uint4 u4; bf16x8 h; } af;
          af.u4 = *(const uint4*)(m1b + (trt + l15) * 64 + so);
          bf16x8 bfv = *(const bf16x8*)(&rhsT[(dv0 + l15) * 72 + so]);
          acc = MFMA(af.h, bfv, acc);
        }
        #pragma unroll
        for (int ks = 0; ks < 4; ks++) {
          int ko = ks * 32 + l4 * 8;
          bf16x8 af = *(const bf16x8*)(&Qb[(trt + l15) * 136 + ko]);
          bf16x8 bfv = *(const bf16x8*)(&S0T[(dv0 + l15) * 136 + ko]);
          acc = MFMA(af, bfv, acc);
        }
        #pragma unroll
        for (int r = 0; r < 4; r++) {
          int t = r0 + trt + l4 * 4 + r;
          conv[(size_t)t * 8192 + 4096 + hv * 128 + dvh + dv0 + l15] = f2bf(acc[r]);
        }
      }
      float lamC = *(const float*)(vb + 256);
      const unsigned short* m2b = M2g + (size_t)bhc * 8192;
      #pragma unroll
      for (int dvt = 0; dvt < 4; dvt++) {
        f32x4 a = S[dvt];
        a[0] *= lamC; a[1] *= lamC; a[2] *= lamC; a[3] *= lamC;
        #pragma unroll
        for (int ks = 0; ks < 2; ks++) {
          int so = ks * 32 + l4 * 8;
          union { uint4 u4; bf16x8 h; } af;
          af.u4 = *(const uint4*)(m2b + (dkb + l15) * 64 + so);
          bf16x8 bfv = *(const bf16x8*)(&rhsT[(dvt * 16 + l15) * 72 + so]);
          a = MFMA(af.h, bfv, a);
        }
        S[dvt] = a;
      }
    }
    __syncthreads();   // B2
    #pragma unroll
    for (int dvt = 0; dvt < 4; dvt++)
      #pragma unroll
      for (int r = 0; r < 4; r++)
        S0T[(dvt * 16 + l15) * 136 + dkb + l4 * 4 + r] = f2bf(S[dvt][r]);
  }
}

// ---------------- gated RMSNorm in-place on o ----------------
__global__ __launch_bounds__(256) void rmsgate_kernel(unsigned short* __restrict__ conv,
                                                      const unsigned short* __restrict__ zg,
                                                      const float* __restrict__ nw) {
  int wid = blockIdx.x * 4 + (threadIdx.x >> 6);
  int lane = threadIdx.x & 63;
  int row = wid >> 5, hv = wid & 31;
  unsigned short* op = conv + (size_t)row * 8192 + 4096 + hv * 128;
  float o0 = bf2f(op[lane]), o1 = bf2f(op[64 + lane]);
  float ss = o0 * o0 + o1 * o1;
  #pragma unroll
  for (int m = 1; m < 64; m <<= 1) ss += __shfl_xor(ss, m);
  float r = rsqrtf(ss * (1.f / 128.f) + 1e-6f);
  const unsigned short* zp = zg + (size_t)row * 4096 + hv * 128;
  float g0 = bf2f(zp[lane]), g1 = bf2f(zp[64 + lane]);
  g0 = g0 / (1.f + expf(-g0));
  g1 = g1 / (1.f + expf(-g1));
  op[lane] = f2bf(o0 * r * g0 * nw[lane]);
  op[64 + lane] = f2bf(o1 * r * g1 * nw[64 + lane]);
}

extern "C" void kernel_launch(void* const* d_in, const int* in_sizes, int n_in,
                              void* d_out, int out_size, void* d_ws, size_t ws_size,
                              hipStream_t stream) {
  (void)in_sizes; (void)n_in; (void)out_size;
  const float* x       = (const float*)d_in[0];
  const float* W_qkv   = (const float*)d_in[1];
  const float* W_z     = (const float*)d_in[2];
  const float* W_b     = (const float*)d_in[3];
  const float* W_a     = (const float*)d_in[4];
  const float* conv_w  = (const float*)d_in[5];
  const float* dt_bias = (const float*)d_in[6];
  const float* A_log   = (const float*)d_in[7];
  const float* nw      = (const float*)d_in[8];
  const float* W_out   = (const float*)d_in[9];
  float* out = (float*)d_out;

  const size_t NEED = 169115648ULL;
  if (ws_size < NEED) return;

  char* ws = (char*)d_ws;
  // slot0 @0 (64MB): WbaT(256KB) -> qkv_bf -> {M1g, M2g} -> WoutT
  unsigned short* WbaT   = (unsigned short*)(ws + 0);
  unsigned short* qkv_bf = (unsigned short*)(ws + 0);
  unsigned short* M1g    = (unsigned short*)(ws + 0);
  unsigned short* M2g    = (unsigned short*)(ws + 16777216);
  unsigned short* WoutT  = (unsigned short*)(ws + 0);
  // zg @64MB (32MB)
  unsigned short* zg     = (unsigned short*)(ws + 67108864);
  // slot2 @96MB (64MB): {WallT 48MB, x_bf 16MB} -> convb
  unsigned short* WallT  = (unsigned short*)(ws + 100663296);
  unsigned short* x_bf   = (unsigned short*)(ws + 100663296 + 50331648);
  unsigned short* convb  = (unsigned short*)(ws + 100663296);
  // tail @160MB
  unsigned short* betab  = (unsigned short*)(ws + 167772160);
  float* gbuf            = (float*)(ws + 168034304);
  unsigned char* vecs    = (unsigned char*)(ws + 168558592);

  const int M = MROWS;

  transpose_multi<<<32896, 256, 0, stream>>>(W_qkv, W_z, W_b, W_a, x, WallT, WbaT, x_bf);

  gemm_ba<<<dim3(1, M / 128), 256, 0, stream>>>(x_bf, 2048, WbaT, 2048,
                                                A_log, dt_bias, betab, gbuf, M, 2048);

  gemm8p<1><<<768, 512, 0, stream>>>(x_bf, 2048, WallT, 2048,
                                     qkv_bf, 8192, 8192, zg, 4096, M, 12288, 2048);

  conv_kernel<<<dim3(64, 64, 2), 256, 0, stream>>>(qkv_bf, conv_w, convb);

  prep_kernel<<<dim3(32, 64), 256, 0, stream>>>(convb, gbuf, betab, M1g, M2g, vecs);

  seq_kernel<<<dim3(2, 64), 512, 0, stream>>>(convb, M1g, M2g, vecs, betab);

  rmsgate_kernel<<<32768, 256, 0, stream>>>(convb, zg, nw);

  transpose_f2b<<<dim3(2048 / 32, 4096 / 32), 256, 0, stream>>>(W_out, WoutT, 4096, 2048);
  gemm256<0, 128><<<256, 512, 0, stream>>>(convb + 4096, 8192, WoutT, 4096, out, 2048, M, 2048, 4096);
}